// Round 19
// baseline (265.180 us; speedup 1.0000x reference)
//
#include <hip/hip_runtime.h>
#include <hip/hip_bf16.h>
#include <math.h>

// SGC: out = log_softmax( (A_norm^2 x) W^T + b )
// (A^2 x) W^T == A^2 (x W^T): propagate 40-dim. Weight factorization:
// z' = dinv.z; pass1 = dd^2*sum (bf16); pass2 = dd*sum + b -> log_softmax.
// Features: 128B-padded bf16 rows (64 cl, 40 valid). SpMM: 8 edges per
// wave-instruction (R18) -- at its line-request-rate floor (~46us/pass;
// R12/14/15/18 all hit ~6.4M line-requests/pass regardless of layout).
// R19: scat and gemm are data-independent -> fused into ONE launch
// (scat blocks || gemm blocks, complementary pipes); dinv pre-scale of z
// moved into sortb (deg already in LDS there). 5 dispatches total.

#define NFEAT 512
#define NCLS  40
#define NBUCK_MAX 512          // buckets = ceil(N/256); N=100000 -> 391
#define CAP   9728             // bucket capacity: mean 8192 + ~17 sigma

typedef __attribute__((ext_vector_type(8))) short bf16x8;
typedef __attribute__((ext_vector_type(4))) float f32x4;

__device__ inline short f2bf(float f) {
    union { float f; unsigned u; } v; v.f = f;
    unsigned r = (v.u + 0x7FFFu + ((v.u >> 16) & 1u)) >> 16;   // RNE
    return (short)r;
}
__device__ inline unsigned pack2bf(float a, float b) {
    return (unsigned)(unsigned short)f2bf(a) | ((unsigned)(unsigned short)f2bf(b) << 16);
}
__device__ inline float bflo(unsigned v) {
    union { unsigned u; float f; } r; r.u = v << 16; return r.f;
}
__device__ inline float bfhi(unsigned v) {
    union { unsigned u; float f; } r; r.u = v & 0xFFFF0000u; return r.f;
}

// ---- K0: W -> MFMA fragment pack + zero bcursor --------------------------
// slot map (same on A side): k = kc*32 + (lane>>4)*8 + j, col = tile*16+(lane&15)

__global__ void wfrag_kernel(const float* __restrict__ W, short* __restrict__ wfrag,
                             int* __restrict__ bcursor) {
    int i = blockIdx.x * blockDim.x + threadIdx.x;
    if (i < NBUCK_MAX) bcursor[i] = 0;
    if (i >= 16 * 3 * 64) return;
    int kc = i / 192, rem = i % 192, tile = rem / 64, lane = rem % 64;
    int c = tile * 16 + (lane & 15);
    int kbase = kc * 32 + ((lane >> 4) << 3);
    bf16x8 out;
    #pragma unroll
    for (int j = 0; j < 8; ++j) {
        float v = (c < NCLS) ? W[(size_t)c * NFEAT + kbase + j] : 0.f;
        out[j] = f2bf(v);
    }
    *(bf16x8*)(wfrag + (size_t)i * 8) = out;
}

// ---- K1: fused [scat || gemm] --------------------------------------------
// blockIdx < CB: radix partition of a 2048-edge chunk (scat7 body).
// blockIdx >= CB: 64-row MFMA gemm tile (z UNSCALED, padded 64-cl rows).

__global__ __launch_bounds__(256) void fused1_kernel(const int* __restrict__ src,
                                                     const int* __restrict__ dst,
                                                     int* __restrict__ bcursor,
                                                     unsigned* __restrict__ bco, int E,
                                                     int CB,
                                                     const float* __restrict__ x,
                                                     const short* __restrict__ wfrag,
                                                     unsigned short* __restrict__ zp,
                                                     int n) {
    __shared__ __align__(16) char smem[2 * 64 * 40 * 2];   // 10.25KB union
    int t = threadIdx.x;

    if (blockIdx.x < (unsigned)CB) {
        // ---------------- scat body ----------------
        int* h    = (int*)smem;            // [512]
        int* h2   = h + NBUCK_MAX;         // [512]
        int* base = h2 + NBUCK_MAX;        // [512] -> 6KB total
        h[t] = 0; h[t + 256] = 0; h2[t] = 0; h2[t + 256] = 0;
        __syncthreads();
        int cb = blockIdx.x * 2048;
        int d[8], s[8];
        bool m[8];
        #pragma unroll
        for (int u = 0; u < 8; ++u) {
            int e = cb + u * 256 + t;
            m[u] = e < E;
            d[u] = m[u] ? __builtin_nontemporal_load(dst + e) : 0;
            s[u] = m[u] ? __builtin_nontemporal_load(src + e) : 0;
            if (m[u]) atomicAdd(&h[d[u] >> 8], 1);
        }
        __syncthreads();
        #pragma unroll
        for (int b = 0; b < 2; ++b) {
            int bb = t + b * 256;
            if (h[bb]) base[bb] = bb * CAP + atomicAdd(&bcursor[bb], h[bb]);
        }
        __syncthreads();
        #pragma unroll
        for (int u = 0; u < 8; ++u) {
            if (m[u]) {
                int b = d[u] >> 8;
                int lp = atomicAdd(&h2[b], 1);
                bco[base[b] + lp] = ((unsigned)s[u] << 8) | (unsigned)(d[u] & 255);
            }
        }
        return;
    }

    // ---------------- gemm body (64 rows, 4 waves) ----------------
    short (*xl)[64 * 40] = (short (*)[64 * 40])smem;
    int w = t >> 6, l = t & 63;
    int lrow = l & 15, lk = l >> 4;
    int rowBase = (blockIdx.x - CB) * 64;
    int srow = t >> 2, skq = t & 3;
    f32x4 acc0 = {0.f, 0.f, 0.f, 0.f}, acc1 = acc0, acc2 = acc0;
    const float* xrow = x + (size_t)(rowBase + srow) * NFEAT + skq * 8;
    bool srOK = (rowBase + srow) < n;
    int aoff = (w * 16 + lrow) * 40 + lk * 8;
    int doff = srow * 40 + skq * 8;

    {   // prologue: stage kc=0
        float4 v0 = make_float4(0.f, 0.f, 0.f, 0.f), v1 = v0;
        if (srOK) { const float4* xp = (const float4*)xrow; v0 = xp[0]; v1 = xp[1]; }
        bf16x8 bv;
        bv[0] = f2bf(v0.x); bv[1] = f2bf(v0.y); bv[2] = f2bf(v0.z); bv[3] = f2bf(v0.w);
        bv[4] = f2bf(v1.x); bv[5] = f2bf(v1.y); bv[6] = f2bf(v1.z); bv[7] = f2bf(v1.w);
        *(bf16x8*)&xl[0][doff] = bv;
    }
    __syncthreads();

    for (int kc = 0; kc < 16; ++kc) {
        int cur = kc & 1;
        float4 v0 = make_float4(0.f, 0.f, 0.f, 0.f), v1 = v0;
        if (kc < 15 && srOK) {                      // issue next chunk early
            const float4* xp = (const float4*)(xrow + (kc + 1) * 32);
            v0 = xp[0]; v1 = xp[1];
        }
        bf16x8 af = *(const bf16x8*)&xl[cur][aoff];
        const bf16x8* wf = (const bf16x8*)(wfrag + (size_t)kc * 3 * 64 * 8);
        bf16x8 b0 = wf[l];
        bf16x8 b1 = wf[64 + l];
        bf16x8 b2 = wf[128 + l];
        acc0 = __builtin_amdgcn_mfma_f32_16x16x32_bf16(af, b0, acc0, 0, 0, 0);
        acc1 = __builtin_amdgcn_mfma_f32_16x16x32_bf16(af, b1, acc1, 0, 0, 0);
        acc2 = __builtin_amdgcn_mfma_f32_16x16x32_bf16(af, b2, acc2, 0, 0, 0);
        if (kc < 15) {
            bf16x8 bv;
            bv[0] = f2bf(v0.x); bv[1] = f2bf(v0.y); bv[2] = f2bf(v0.z); bv[3] = f2bf(v0.w);
            bv[4] = f2bf(v1.x); bv[5] = f2bf(v1.y); bv[6] = f2bf(v1.z); bv[7] = f2bf(v1.w);
            *(bf16x8*)&xl[cur ^ 1][doff] = bv;
            __syncthreads();
        }
    }
    int r0 = rowBase + w * 16 + lk * 4;    // C/D: col=lane&15, row=(lane>>4)*4+reg
    #pragma unroll
    for (int reg = 0; reg < 4; ++reg) {
        int row = r0 + reg;
        if (row < n) {
            unsigned short* zr = zp + (size_t)row * 64;
            zr[lrow]      = (unsigned short)f2bf(acc0[reg]);
            zr[16 + lrow] = (unsigned short)f2bf(acc1[reg]);
            zr[32 + lrow] = (lrow < 8) ? (unsigned short)f2bf(acc2[reg]) : 0;
            zr[48 + lrow] = 0;
        }
    }
}

// ---- K2: per-bucket counting sort + z' = dinv.z scale --------------------

__global__ __launch_bounds__(256) void sortb4_kernel(const unsigned* __restrict__ bco,
                                                     const int* __restrict__ bcursor,
                                                     int4* __restrict__ rowinfo,
                                                     int* __restrict__ csr_src,
                                                     unsigned short* __restrict__ zp,
                                                     int N) {
    __shared__ int deg[256], ex[256], sc[256];
    int b = blockIdx.x, t = threadIdx.x;
    int lo = b * 256;
    int nn = N - lo; if (nn > 256) nn = 256;
    int ebeg = b * CAP;
    int ecnt = bcursor[b];

    deg[t] = 0;
    __syncthreads();
    for (int i = t; i < ecnt; i += 256)
        atomicAdd(&deg[bco[ebeg + i] & 255u], 1);
    __syncthreads();
    int v = deg[t];
    sc[t] = v;
    __syncthreads();
    for (int off = 1; off < 256; off <<= 1) {
        int u = (t >= off) ? sc[t - off] : 0;
        __syncthreads();
        sc[t] += u;
        __syncthreads();
    }
    int ext = sc[t] - v;            // exclusive prefix
    ex[t] = ext;
    if (t < nn) {
        float di = rsqrtf((float)(v + 1));          // +1 self-loop
        int4 ri;
        ri.x = ebeg + ext;
        ri.y = v;
        ri.z = __float_as_int(di);
        ri.w = 0;
        rowinfo[lo + t] = ri;
    }
    __syncthreads();
    for (int i = t; i < ecnt; i += 256) {
        unsigned e = bco[ebeg + i];
        int p = atomicAdd(&ex[e & 255u], 1);
        csr_src[ebeg + p] = (int)(e >> 8);
    }
    // z' = dinv * z (coalesced; deg[] still valid, 32 dwords per row)
    for (int idx = t; idx < nn * 32; idx += 256) {
        int row = idx >> 5, c = idx & 31;
        float di = rsqrtf((float)(deg[row] + 1));
        unsigned* zr = (unsigned*)(zp + (size_t)(lo + row) * 64);
        unsigned vv = zr[c];
        zr[c] = pack2bf(bflo(vv) * di, bfhi(vv) * di);
    }
}

// ---- unweighted pull-SpMM: 8 edges per wave-instruction (R18) ------------

template <bool FINAL>
__global__ __launch_bounds__(256) void spmm12_kernel(const unsigned short* __restrict__ in,
                                                     const int4* __restrict__ rowinfo,
                                                     const int* __restrict__ csr,
                                                     const float* __restrict__ bias,
                                                     unsigned short* __restrict__ outP,
                                                     float* __restrict__ outF, int n) {
    int wv = (int)((blockIdx.x * (size_t)blockDim.x + threadIdx.x) >> 6);
    wv = __builtin_amdgcn_readfirstlane(wv);        // force SGPR (uniform)
    if (wv >= n) return;
    int lane = threadIdx.x & 63;
    int g  = lane >> 3;                             // edge group 0..7
    int oc = lane & 7;                              // class octet 0..7

    const char* rowb = (const char*)in + oc * 16;   // + s*128 per gather

    int4 ri = rowinfo[wv];                          // s_load_dwordx4
    int beg = ri.x, tot = ri.y;
    float dd = __int_as_float(ri.z);

    float a0 = 0.f, a1 = 0.f, a2 = 0.f, a3 = 0.f,
          a4 = 0.f, a5 = 0.f, a6 = 0.f, a7 = 0.f;

#define ACC_ADD(V)                                                     \
    { a0 += bflo((V).x); a1 += bfhi((V).x); a2 += bflo((V).y);         \
      a3 += bfhi((V).y); a4 += bflo((V).z); a5 += bfhi((V).z);         \
      a6 += bflo((V).w); a7 += bfhi((V).w); }

    if (g == 0) {                                   // self term in group 0
        uint4 v = *(const uint4*)(rowb + (size_t)wv * 128);
        ACC_ADD(v);
    }

    int j = 0;
    for (; j + 32 <= tot; j += 32) {                // 4 gathers x 8 edges
        int s0 = csr[beg + j + g];
        int s1 = csr[beg + j + 8 + g];
        int s2 = csr[beg + j + 16 + g];
        int s3 = csr[beg + j + 24 + g];
        uint4 v0 = *(const uint4*)(rowb + (size_t)s0 * 128);
        uint4 v1 = *(const uint4*)(rowb + (size_t)s1 * 128);
        uint4 v2 = *(const uint4*)(rowb + (size_t)s2 * 128);
        uint4 v3 = *(const uint4*)(rowb + (size_t)s3 * 128);
        ACC_ADD(v0); ACC_ADD(v1); ACC_ADD(v2); ACC_ADD(v3);
    }
    for (; j < tot; j += 8) {                       // masked 8-edge steps
        if (g < tot - j) {
            int s = csr[beg + j + g];
            uint4 v = *(const uint4*)(rowb + (size_t)s * 128);
            ACC_ADD(v);
        }
    }
#undef ACC_ADD

    // reduce across edge groups (lanes differing in bits 3..5)
    #pragma unroll
    for (int off = 8; off <= 32; off <<= 1) {
        a0 += __shfl_xor(a0, off, 64); a1 += __shfl_xor(a1, off, 64);
        a2 += __shfl_xor(a2, off, 64); a3 += __shfl_xor(a3, off, 64);
        a4 += __shfl_xor(a4, off, 64); a5 += __shfl_xor(a5, off, 64);
        a6 += __shfl_xor(a6, off, 64); a7 += __shfl_xor(a7, off, 64);
    }

    if (!FINAL) {
        if (g == 0) {                               // lanes 0..7 write the row
            float s2 = dd * dd;
            uint4 o;
            o.x = pack2bf(a0 * s2, a1 * s2);
            o.y = pack2bf(a2 * s2, a3 * s2);
            o.z = pack2bf(a4 * s2, a5 * s2);
            o.w = pack2bf(a6 * s2, a7 * s2);
            *(uint4*)((char*)outP + (size_t)wv * 128 + oc * 16) = o;
        }
    } else {
        float b0 = 0.f, b1 = 0.f, b2 = 0.f, b3 = 0.f,
              b4 = 0.f, b5 = 0.f, b6 = 0.f, b7 = 0.f;
        if (oc < 5) {                               // bias octets 0..4 valid
            float4 q0 = ((const float4*)bias)[oc * 2];
            float4 q1 = ((const float4*)bias)[oc * 2 + 1];
            b0 = q0.x; b1 = q0.y; b2 = q0.z; b3 = q0.w;
            b4 = q1.x; b5 = q1.y; b6 = q1.z; b7 = q1.w;
        }
        bool valid = oc < 5;
        float v0 = valid ? a0 * dd + b0 : -INFINITY;
        float v1 = valid ? a1 * dd + b1 : -INFINITY;
        float v2 = valid ? a2 * dd + b2 : -INFINITY;
        float v3 = valid ? a3 * dd + b3 : -INFINITY;
        float v4 = valid ? a4 * dd + b4 : -INFINITY;
        float v5 = valid ? a5 * dd + b5 : -INFINITY;
        float v6 = valid ? a6 * dd + b6 : -INFINITY;
        float v7 = valid ? a7 * dd + b7 : -INFINITY;
        float m = fmaxf(fmaxf(fmaxf(v0, v1), fmaxf(v2, v3)),
                        fmaxf(fmaxf(v4, v5), fmaxf(v6, v7)));
        #pragma unroll
        for (int off = 1; off <= 4; off <<= 1) m = fmaxf(m, __shfl_xor(m, off, 64));
        float es = 0.f;
        if (valid)
            es = expf(v0 - m) + expf(v1 - m) + expf(v2 - m) + expf(v3 - m)
               + expf(v4 - m) + expf(v5 - m) + expf(v6 - m) + expf(v7 - m);
        #pragma unroll
        for (int off = 1; off <= 4; off <<= 1) es += __shfl_xor(es, off, 64);
        float lse = logf(es) + m;
        if (g == 0 && valid) {
            float* op = outF + (size_t)wv * NCLS + oc * 8;
            float4 o0 = make_float4(v0 - lse, v1 - lse, v2 - lse, v3 - lse);
            float4 o1 = make_float4(v4 - lse, v5 - lse, v6 - lse, v7 - lse);
            *(float4*)op = o0;
            *(float4*)(op + 4) = o1;
        }
    }
}

// ---- driver -------------------------------------------------------------

extern "C" void kernel_launch(void* const* d_in, const int* in_sizes, int n_in,
                              void* d_out, int out_size, void* d_ws, size_t ws_size,
                              hipStream_t stream) {
    const float* x  = (const float*)d_in[0];
    const int*   ei = (const int*)d_in[1];
    const float* W  = (const float*)d_in[2];
    const float* b  = (const float*)d_in[3];

    const int N = in_sizes[0] / NFEAT;
    const int E = in_sizes[1] / 2;
    const int* src = ei;
    const int* dst = ei + E;
    const int nbuck = (N + 255) >> 8;      // 391

    char* p = (char*)d_ws;
    auto alloc = [&](size_t bytes) -> void* {
        void* r = (void*)p;
        p += (bytes + 255) & ~(size_t)255;
        return r;
    };
    int*      bcursor = (int*)     alloc((size_t)NBUCK_MAX * 4);
    int4*     rowinfo = (int4*)    alloc((size_t)N * 16);
    unsigned* bco     = (unsigned*)alloc((size_t)nbuck * CAP * 4 + 64);
    int*      csr_src = (int*)     alloc((size_t)nbuck * CAP * 4 + 64);
    short*    wfrag   = (short*)   alloc((size_t)16 * 3 * 64 * 8 * 2);
    unsigned short* zp  = (unsigned short*)alloc((size_t)N * 64 * 2);   // 12.8MB padded
    unsigned short* h1p = (unsigned short*)alloc((size_t)N * 64 * 2);   // 12.8MB padded

    wfrag_kernel<<<12, 256, 0, stream>>>(W, wfrag, bcursor);   // also zeros bcursor

    int CB = (E + 2047) / 2048;            // 1563 scat blocks
    int GB = (N + 63) / 64;                // 1563 gemm blocks
    fused1_kernel<<<CB + GB, 256, 0, stream>>>(src, dst, bcursor, bco, E, CB,
                                               x, wfrag, zp, N);

    sortb4_kernel<<<nbuck, 256, 0, stream>>>(bco, bcursor, rowinfo, csr_src, zp, N);

    int wb = (int)(((size_t)N * 64 + 255) / 256);
    spmm12_kernel<false><<<wb, 256, 0, stream>>>(zp, rowinfo, csr_src, b, h1p, nullptr, N);
    spmm12_kernel<true ><<<wb, 256, 0, stream>>>(h1p, rowinfo, csr_src, b, nullptr,
                                                 (float*)d_out, N);
}

// Round 20
// 257.465 us; speedup vs baseline: 1.0300x; 1.0300x over previous
//
#include <hip/hip_runtime.h>
#include <hip/hip_bf16.h>
#include <math.h>

// SGC: out = log_softmax( (A_norm^2 x) W^T + b )
// (A^2 x) W^T == A^2 (x W^T): propagate 40-dim. Weight factorization:
// z' = dinv.z; pass1 = dd^2*sum (bf16); pass2 = dd*sum + b -> log_softmax.
// R20 = R18 verbatim (best verified: 260.76us). Features in 128B-padded
// bf16 rows; SpMM gathers 8 edges/wave-instruction; spmm is at the
// cache-line request-rate floor (4 implementations converge at ~46us/pass).
// CSR build: padded radix buckets of 256 nodes + counting sort.

#define NFEAT 512
#define NCLS  40
#define NBUCK_MAX 512          // buckets = ceil(N/256); N=100000 -> 391
#define CAP   9728             // bucket capacity: mean 8192 + ~17 sigma

typedef __attribute__((ext_vector_type(8))) short bf16x8;
typedef __attribute__((ext_vector_type(4))) float f32x4;

__device__ inline short f2bf(float f) {
    union { float f; unsigned u; } v; v.f = f;
    unsigned r = (v.u + 0x7FFFu + ((v.u >> 16) & 1u)) >> 16;   // RNE
    return (short)r;
}
__device__ inline unsigned pack2bf(float a, float b) {
    return (unsigned)(unsigned short)f2bf(a) | ((unsigned)(unsigned short)f2bf(b) << 16);
}
__device__ inline float bflo(unsigned v) {
    union { unsigned u; float f; } r; r.u = v << 16; return r.f;
}
__device__ inline float bfhi(unsigned v) {
    union { unsigned u; float f; } r; r.u = v & 0xFFFF0000u; return r.f;
}

// ---- 1. radix partition into padded buckets: bco[b*CAP+i] = (s<<8)|(d&255)

__global__ __launch_bounds__(256) void scat7_kernel(const int* __restrict__ src,
                                                    const int* __restrict__ dst,
                                                    int* __restrict__ bcursor,
                                                    unsigned* __restrict__ bco, int E) {
    __shared__ int h[NBUCK_MAX], h2[NBUCK_MAX], base[NBUCK_MAX];
    int t = threadIdx.x;
    h[t] = 0; h[t + 256] = 0; h2[t] = 0; h2[t + 256] = 0;
    __syncthreads();
    int cb = blockIdx.x * 2048;
    int d[8], s[8];
    bool m[8];
    #pragma unroll
    for (int u = 0; u < 8; ++u) {
        int e = cb + u * 256 + t;
        m[u] = e < E;
        d[u] = m[u] ? __builtin_nontemporal_load(dst + e) : 0;
        s[u] = m[u] ? __builtin_nontemporal_load(src + e) : 0;
        if (m[u]) atomicAdd(&h[d[u] >> 8], 1);
    }
    __syncthreads();
    #pragma unroll
    for (int b = 0; b < 2; ++b) {
        int bb = t + b * 256;
        if (h[bb]) base[bb] = bb * CAP + atomicAdd(&bcursor[bb], h[bb]);
    }
    __syncthreads();
    #pragma unroll
    for (int u = 0; u < 8; ++u) {
        if (m[u]) {
            int b = d[u] >> 8;
            int lp = atomicAdd(&h2[b], 1);
            bco[base[b] + lp] = ((unsigned)s[u] << 8) | (unsigned)(d[u] & 255);
        }
    }
}

// ---- 2. per-bucket counting sort -> rowinfo{beg,cnt,dinv}, dinv, csr_src --

__global__ __launch_bounds__(256) void sortb3_kernel(const unsigned* __restrict__ bco,
                                                     const int* __restrict__ bcursor,
                                                     int4* __restrict__ rowinfo,
                                                     float* __restrict__ dinv,
                                                     int* __restrict__ csr_src, int N) {
    __shared__ int deg[256], ex[256], sc[256];
    int b = blockIdx.x, t = threadIdx.x;
    int lo = b * 256;
    int nn = N - lo; if (nn > 256) nn = 256;
    int ebeg = b * CAP;
    int ecnt = bcursor[b];

    deg[t] = 0;
    __syncthreads();
    for (int i = t; i < ecnt; i += 256)
        atomicAdd(&deg[bco[ebeg + i] & 255u], 1);
    __syncthreads();
    int v = deg[t];
    sc[t] = v;
    __syncthreads();
    for (int off = 1; off < 256; off <<= 1) {
        int u = (t >= off) ? sc[t - off] : 0;
        __syncthreads();
        sc[t] += u;
        __syncthreads();
    }
    int ext = sc[t] - v;            // exclusive prefix
    ex[t] = ext;
    if (t < nn) {
        float di = rsqrtf((float)(v + 1));          // +1 self-loop
        int4 ri;
        ri.x = ebeg + ext;
        ri.y = v;
        ri.z = __float_as_int(di);
        ri.w = 0;
        rowinfo[lo + t] = ri;
        dinv[lo + t]    = di;
    }
    __syncthreads();
    for (int i = t; i < ecnt; i += 256) {
        unsigned e = bco[ebeg + i];
        int p = atomicAdd(&ex[e & 255u], 1);
        csr_src[ebeg + p] = (int)(e >> 8);
    }
}

// ---- W -> MFMA fragment pack (+ zero bcursor: runs FIRST) ----------------

__global__ void wfrag_kernel(const float* __restrict__ W, short* __restrict__ wfrag,
                             int* __restrict__ bcursor) {
    int i = blockIdx.x * blockDim.x + threadIdx.x;
    if (i < NBUCK_MAX) bcursor[i] = 0;
    if (i >= 16 * 3 * 64) return;
    int kc = i / 192, rem = i % 192, tile = rem / 64, lane = rem % 64;
    int c = tile * 16 + (lane & 15);
    int kbase = kc * 32 + ((lane >> 4) << 3);
    bf16x8 out;
    #pragma unroll
    for (int j = 0; j < 8; ++j) {
        float v = (c < NCLS) ? W[(size_t)c * NFEAT + kbase + j] : 0.f;
        out[j] = f2bf(v);
    }
    *(bf16x8*)(wfrag + (size_t)i * 8) = out;
}

// ---- z' = dinv.(x @ W^T) via MFMA bf16, 128B-padded row output -----------

__global__ __launch_bounds__(512) void gemm7_kernel(const float* __restrict__ x,
                                                    const short* __restrict__ wfrag,
                                                    const float* __restrict__ dinv,
                                                    unsigned short* __restrict__ zp, int n) {
    __shared__ short xl[2][128 * 40];
    int t = threadIdx.x;
    int w = t >> 6, l = t & 63;
    int lrow = l & 15, lk = l >> 4;
    int rowBase = blockIdx.x * 128;
    int srow = t >> 2, skq = t & 3;
    f32x4 acc0 = {0.f, 0.f, 0.f, 0.f}, acc1 = acc0, acc2 = acc0;
    const float* xrow = x + (size_t)(rowBase + srow) * NFEAT + skq * 8;
    bool srOK = (rowBase + srow) < n;
    int aoff = (w * 16 + lrow) * 40 + lk * 8;
    int doff = srow * 40 + skq * 8;

    {   // prologue: stage kc=0
        float4 v0 = make_float4(0.f, 0.f, 0.f, 0.f), v1 = v0;
        if (srOK) { const float4* xp = (const float4*)xrow; v0 = xp[0]; v1 = xp[1]; }
        bf16x8 bv;
        bv[0] = f2bf(v0.x); bv[1] = f2bf(v0.y); bv[2] = f2bf(v0.z); bv[3] = f2bf(v0.w);
        bv[4] = f2bf(v1.x); bv[5] = f2bf(v1.y); bv[6] = f2bf(v1.z); bv[7] = f2bf(v1.w);
        *(bf16x8*)&xl[0][doff] = bv;
    }
    __syncthreads();

    for (int kc = 0; kc < 16; ++kc) {
        int cur = kc & 1;
        float4 v0 = make_float4(0.f, 0.f, 0.f, 0.f), v1 = v0;
        if (kc < 15 && srOK) {                      // issue next chunk early
            const float4* xp = (const float4*)(xrow + (kc + 1) * 32);
            v0 = xp[0]; v1 = xp[1];
        }
        bf16x8 af = *(const bf16x8*)&xl[cur][aoff];
        const bf16x8* wf = (const bf16x8*)(wfrag + (size_t)kc * 3 * 64 * 8);
        bf16x8 b0 = wf[l];
        bf16x8 b1 = wf[64 + l];
        bf16x8 b2 = wf[128 + l];
        acc0 = __builtin_amdgcn_mfma_f32_16x16x32_bf16(af, b0, acc0, 0, 0, 0);
        acc1 = __builtin_amdgcn_mfma_f32_16x16x32_bf16(af, b1, acc1, 0, 0, 0);
        acc2 = __builtin_amdgcn_mfma_f32_16x16x32_bf16(af, b2, acc2, 0, 0, 0);
        if (kc < 15) {
            bf16x8 bv;
            bv[0] = f2bf(v0.x); bv[1] = f2bf(v0.y); bv[2] = f2bf(v0.z); bv[3] = f2bf(v0.w);
            bv[4] = f2bf(v1.x); bv[5] = f2bf(v1.y); bv[6] = f2bf(v1.z); bv[7] = f2bf(v1.w);
            *(bf16x8*)&xl[cur ^ 1][doff] = bv;
            __syncthreads();
        }
    }
    int r0 = rowBase + w * 16 + lk * 4;    // C/D: col=lane&15, row=(lane>>4)*4+reg
    #pragma unroll
    for (int reg = 0; reg < 4; ++reg) {
        int row = r0 + reg;
        if (row < n) {
            float sc = dinv[row];                   // pre-scale: z' = dinv*z
            unsigned short* zr = zp + (size_t)row * 64;
            zr[lrow]      = (unsigned short)f2bf(acc0[reg] * sc);
            zr[16 + lrow] = (unsigned short)f2bf(acc1[reg] * sc);
            zr[32 + lrow] = (lrow < 8) ? (unsigned short)f2bf(acc2[reg] * sc) : 0;
            zr[48 + lrow] = 0;
        }
    }
}

// ---- unweighted pull-SpMM: 8 edges per wave-instruction ------------------
// lane = group g=lane>>3 (edge) x octet oc=lane&7 (classes 8oc..8oc+7).
// Per 8 edges: 1 idx vector-load + 1 dwordx4 gather. No register arrays.

template <bool FINAL>
__global__ __launch_bounds__(256) void spmm12_kernel(const unsigned short* __restrict__ in,
                                                     const int4* __restrict__ rowinfo,
                                                     const int* __restrict__ csr,
                                                     const float* __restrict__ bias,
                                                     unsigned short* __restrict__ outP,
                                                     float* __restrict__ outF, int n) {
    int wv = (int)((blockIdx.x * (size_t)blockDim.x + threadIdx.x) >> 6);
    wv = __builtin_amdgcn_readfirstlane(wv);        // force SGPR (uniform)
    if (wv >= n) return;
    int lane = threadIdx.x & 63;
    int g  = lane >> 3;                             // edge group 0..7
    int oc = lane & 7;                              // class octet 0..7

    const char* rowb = (const char*)in + oc * 16;   // + s*128 per gather

    int4 ri = rowinfo[wv];                          // s_load_dwordx4
    int beg = ri.x, tot = ri.y;
    float dd = __int_as_float(ri.z);

    float a0 = 0.f, a1 = 0.f, a2 = 0.f, a3 = 0.f,
          a4 = 0.f, a5 = 0.f, a6 = 0.f, a7 = 0.f;

#define ACC_ADD(V)                                                     \
    { a0 += bflo((V).x); a1 += bfhi((V).x); a2 += bflo((V).y);         \
      a3 += bfhi((V).y); a4 += bflo((V).z); a5 += bfhi((V).z);         \
      a6 += bflo((V).w); a7 += bfhi((V).w); }

    if (g == 0) {                                   // self term in group 0
        uint4 v = *(const uint4*)(rowb + (size_t)wv * 128);
        ACC_ADD(v);
    }

    int j = 0;
    for (; j + 32 <= tot; j += 32) {                // 4 gathers x 8 edges
        int s0 = csr[beg + j + g];
        int s1 = csr[beg + j + 8 + g];
        int s2 = csr[beg + j + 16 + g];
        int s3 = csr[beg + j + 24 + g];
        uint4 v0 = *(const uint4*)(rowb + (size_t)s0 * 128);
        uint4 v1 = *(const uint4*)(rowb + (size_t)s1 * 128);
        uint4 v2 = *(const uint4*)(rowb + (size_t)s2 * 128);
        uint4 v3 = *(const uint4*)(rowb + (size_t)s3 * 128);
        ACC_ADD(v0); ACC_ADD(v1); ACC_ADD(v2); ACC_ADD(v3);
    }
    for (; j < tot; j += 8) {                       // masked 8-edge steps
        if (g < tot - j) {
            int s = csr[beg + j + g];
            uint4 v = *(const uint4*)(rowb + (size_t)s * 128);
            ACC_ADD(v);
        }
    }
#undef ACC_ADD

    // reduce across edge groups (lanes differing in bits 3..5)
    #pragma unroll
    for (int off = 8; off <= 32; off <<= 1) {
        a0 += __shfl_xor(a0, off, 64); a1 += __shfl_xor(a1, off, 64);
        a2 += __shfl_xor(a2, off, 64); a3 += __shfl_xor(a3, off, 64);
        a4 += __shfl_xor(a4, off, 64); a5 += __shfl_xor(a5, off, 64);
        a6 += __shfl_xor(a6, off, 64); a7 += __shfl_xor(a7, off, 64);
    }

    if (!FINAL) {
        if (g == 0) {                               // lanes 0..7 write the row
            float s2 = dd * dd;
            uint4 o;
            o.x = pack2bf(a0 * s2, a1 * s2);
            o.y = pack2bf(a2 * s2, a3 * s2);
            o.z = pack2bf(a4 * s2, a5 * s2);
            o.w = pack2bf(a6 * s2, a7 * s2);
            *(uint4*)((char*)outP + (size_t)wv * 128 + oc * 16) = o;
        }
    } else {
        float b0 = 0.f, b1 = 0.f, b2 = 0.f, b3 = 0.f,
              b4 = 0.f, b5 = 0.f, b6 = 0.f, b7 = 0.f;
        if (oc < 5) {                               // bias octets 0..4 valid
            float4 q0 = ((const float4*)bias)[oc * 2];
            float4 q1 = ((const float4*)bias)[oc * 2 + 1];
            b0 = q0.x; b1 = q0.y; b2 = q0.z; b3 = q0.w;
            b4 = q1.x; b5 = q1.y; b6 = q1.z; b7 = q1.w;
        }
        bool valid = oc < 5;
        float v0 = valid ? a0 * dd + b0 : -INFINITY;
        float v1 = valid ? a1 * dd + b1 : -INFINITY;
        float v2 = valid ? a2 * dd + b2 : -INFINITY;
        float v3 = valid ? a3 * dd + b3 : -INFINITY;
        float v4 = valid ? a4 * dd + b4 : -INFINITY;
        float v5 = valid ? a5 * dd + b5 : -INFINITY;
        float v6 = valid ? a6 * dd + b6 : -INFINITY;
        float v7 = valid ? a7 * dd + b7 : -INFINITY;
        float m = fmaxf(fmaxf(fmaxf(v0, v1), fmaxf(v2, v3)),
                        fmaxf(fmaxf(v4, v5), fmaxf(v6, v7)));
        #pragma unroll
        for (int off = 1; off <= 4; off <<= 1) m = fmaxf(m, __shfl_xor(m, off, 64));
        float es = 0.f;
        if (valid)
            es = expf(v0 - m) + expf(v1 - m) + expf(v2 - m) + expf(v3 - m)
               + expf(v4 - m) + expf(v5 - m) + expf(v6 - m) + expf(v7 - m);
        #pragma unroll
        for (int off = 1; off <= 4; off <<= 1) es += __shfl_xor(es, off, 64);
        float lse = logf(es) + m;
        if (g == 0 && valid) {
            float* op = outF + (size_t)wv * NCLS + oc * 8;
            float4 o0 = make_float4(v0 - lse, v1 - lse, v2 - lse, v3 - lse);
            float4 o1 = make_float4(v4 - lse, v5 - lse, v6 - lse, v7 - lse);
            *(float4*)op = o0;
            *(float4*)(op + 4) = o1;
        }
    }
}

// ---- driver -------------------------------------------------------------

extern "C" void kernel_launch(void* const* d_in, const int* in_sizes, int n_in,
                              void* d_out, int out_size, void* d_ws, size_t ws_size,
                              hipStream_t stream) {
    const float* x  = (const float*)d_in[0];
    const int*   ei = (const int*)d_in[1];
    const float* W  = (const float*)d_in[2];
    const float* b  = (const float*)d_in[3];

    const int N = in_sizes[0] / NFEAT;
    const int E = in_sizes[1] / 2;
    const int* src = ei;
    const int* dst = ei + E;
    const int nbuck = (N + 255) >> 8;      // 391

    char* p = (char*)d_ws;
    auto alloc = [&](size_t bytes) -> void* {
        void* r = (void*)p;
        p += (bytes + 255) & ~(size_t)255;
        return r;
    };
    int*      bcursor = (int*)     alloc((size_t)NBUCK_MAX * 4);
    int4*     rowinfo = (int4*)    alloc((size_t)N * 16);
    float*    dinv    = (float*)   alloc((size_t)N * 4);
    unsigned* bco     = (unsigned*)alloc((size_t)nbuck * CAP * 4 + 64);
    int*      csr_src = (int*)     alloc((size_t)nbuck * CAP * 4 + 64);
    short*    wfrag   = (short*)   alloc((size_t)16 * 3 * 64 * 8 * 2);
    unsigned short* zp  = (unsigned short*)alloc((size_t)N * 64 * 2);   // 12.8MB padded
    unsigned short* h1p = (unsigned short*)alloc((size_t)N * 64 * 2);   // 12.8MB padded

    wfrag_kernel<<<12, 256, 0, stream>>>(W, wfrag, bcursor);   // also zeros bcursor

    int cb = (E + 2047) / 2048;
    scat7_kernel<<<cb, 256, 0, stream>>>(src, dst, bcursor, bco, E);
    sortb3_kernel<<<nbuck, 256, 0, stream>>>(bco, bcursor, rowinfo, dinv, csr_src, N);

    gemm7_kernel<<<(N + 127) / 128, 512, 0, stream>>>(x, wfrag, dinv, zp, N);

    int wb = (int)(((size_t)N * 64 + 255) / 256);
    spmm12_kernel<false><<<wb, 256, 0, stream>>>(zp, rowinfo, csr_src, b, h1p, nullptr, N);
    spmm12_kernel<true ><<<wb, 256, 0, stream>>>(h1p, rowinfo, csr_src, b, nullptr,
                                                 (float*)d_out, N);
}